// Round 12
// baseline (1157.564 us; speedup 1.0000x reference)
//
#include <hip/hip_runtime.h>
#include <hip/hip_bf16.h>
#include <math.h>

#define S_LEN 2048
#define NBATCH 32
#define DIM 384
#define NTOK (NBATCH * S_LEN)

typedef __hip_bfloat16 bf16;
typedef __attribute__((ext_vector_type(8))) short short8v;
typedef __attribute__((ext_vector_type(4))) float f32x4;
typedef __attribute__((ext_vector_type(2))) unsigned int uint2v;
typedef __attribute__((ext_vector_type(4))) int int4v;
typedef short8v fragT;

#define LDAP 72  // padded LDS leading dim (halfwords) — attn kernel only

__device__ __forceinline__ float bf2f(unsigned short u) {
  union { unsigned int i; float f; } c; c.i = ((unsigned int)u) << 16; return c.f;
}

// direct global->LDS DMA, 16B per lane; LDS dest = wave-uniform base + lane*16
__device__ __forceinline__ void gl16(const bf16* g, short* l) {
  __builtin_amdgcn_global_load_lds(
      (const __attribute__((address_space(1))) void*)g,
      (__attribute__((address_space(3))) void*)l, 16, 0, 0);
}

// ---------------- weight fp32 -> bf16 conversion ----------------
__global__ __launch_bounds__(256) void conv_kernel(const float* __restrict__ we,
                                                   const float* __restrict__ wp,
                                                   bf16* __restrict__ web,
                                                   bf16* __restrict__ wpb) {
  int i = blockIdx.x * 256 + threadIdx.x;
  int stride = gridDim.x * 256;
  for (int j = i; j < 1632 * 384; j += stride) web[j] = __float2bfloat16(we[j]);
  for (int j = i; j < 384 * 768; j += stride) wpb[j] = __float2bfloat16(wp[j]);
}

// ---------------- LayerNorm: x (fp32) -> xn (bf16) ----------------
__global__ __launch_bounds__(256) void ln_kernel(const float* __restrict__ x,
                                                 const float* __restrict__ nw,
                                                 bf16* __restrict__ xn) {
  int token = blockIdx.x * 4 + (threadIdx.x >> 6);
  int lane = threadIdx.x & 63;
  const float* xr = x + (size_t)token * DIM;
  float v[6];
  float s = 0.f, sq = 0.f;
#pragma unroll
  for (int j = 0; j < 6; ++j) {
    v[j] = xr[lane + j * 64];
    s += v[j];
    sq += v[j] * v[j];
  }
#pragma unroll
  for (int o = 32; o; o >>= 1) {
    s += __shfl_xor(s, o);
    sq += __shfl_xor(sq, o);
  }
  float mu = s * (1.f / DIM);
  float var = sq * (1.f / DIM) - mu * mu;
  float rs = rsqrtf(var + 1e-5f);
  bf16* xo = xn + (size_t)token * DIM;
#pragma unroll
  for (int j = 0; j < 6; ++j) {
    int c = lane + j * 64;
    xo[c] = __float2bfloat16((v[j] - mu) * rs * nw[c]);
  }
}

// ---------------- expand GEMM: 512-thread, BN=256, 3 blocks/CU ------------
// BM=128 x BN=256, BK=64, 6 K-steps, 8 waves (2M x 4N), 48 KB LDS single buf,
// 2 barriers/step. Linear LDS + pre-swizzled source (chunk ^= row&7).
// Grid 3584 = 512 x * 7 y, XCD-swizzled y-inner (A-tile L2-hot).
// y=0: qk cols 0..95 (cols 96.. garbage, not stored). y=1..6: 128 lin +
// 128 pre cols; B rows interleaved in 32-row [lin|pre] groups so each wave's
// ni and ni+2 frags are matching lin/pre pairs (register-local GEGLU).
__global__ __launch_bounds__(512, 6) void expand_gl_kernel(
    const bf16* __restrict__ xn, const bf16* __restrict__ web,
    bf16* __restrict__ qkb, bf16* __restrict__ gl, bf16* __restrict__ gv) {
  __shared__ short As2[128 * 64];  // 16384 B, linear
  __shared__ short Bs2[256 * 64];  // 32768 B, linear
  int t = threadIdx.x;
  int lane = t & 63, w = t >> 6;   // w 0..7
  int wr = w >> 2, wc = w & 3;     // 2M x 4N
  int m = lane & 15, g = lane >> 4;

  int bid = blockIdx.x;
  int logical = (bid & 7) * 448 + (bid >> 3);
  int xt = logical / 7, y = logical % 7;
  int row0 = xt * 128;

  int lr = lane >> 3;      // row within 8-row group
  int s8 = lane & 7;       // LDS slot this lane fills
  int cs = s8 ^ lr;        // swizzled source chunk (involution)

  const bf16* ga[2];
  const bf16* gb[4];
#pragma unroll
  for (int i = 0; i < 2; ++i) {
    int row = w * 16 + i * 8 + lr;  // 0..127
    ga[i] = xn + (size_t)(row0 + row) * 384 + cs * 8;
  }
#pragma unroll
  for (int i = 0; i < 4; ++i) {
    int row = w * 32 + i * 8 + lr;  // 0..255
    int brow;
    if (y == 0) brow = (row < 96) ? row : 95;  // clamp: harmless garbage
    else {
      int q = row >> 5, nn = row & 31;
      int base = (y - 1) * 128 + (q >> 1) * 32 + nn;
      brow = (q & 1) ? (864 + base) : (96 + base);
    }
    gb[i] = web + (size_t)brow * 384 + cs * 8;
  }
  short* la[2];
  short* lb[4];
#pragma unroll
  for (int i = 0; i < 2; ++i) la[i] = As2 + (w * 16 + i * 8) * 64;
#pragma unroll
  for (int i = 0; i < 4; ++i) lb[i] = Bs2 + (w * 32 + i * 8) * 64;

  f32x4 acc[4][4];
#pragma unroll
  for (int i = 0; i < 4; ++i)
#pragma unroll
    for (int j = 0; j < 4; ++j) acc[i][j] = (f32x4){0.f, 0.f, 0.f, 0.f};

#pragma unroll
  for (int kt = 0; kt < 6; ++kt) {
    __syncthreads();  // prior step's ds_reads done before overwrite
#pragma unroll
    for (int i = 0; i < 2; ++i) gl16(ga[i] + kt * 64, la[i]);
#pragma unroll
    for (int i = 0; i < 4; ++i) gl16(gb[i] + kt * 64, lb[i]);
    __syncthreads();  // vmcnt(0) drained before barrier -> LDS valid
#pragma unroll
    for (int ks = 0; ks < 2; ++ks) {
      int c = ks * 4 + g;
      int cxm = c ^ (m & 7);
      fragT af[4], bfv[4];
#pragma unroll
      for (int mi = 0; mi < 4; ++mi) {
        int R = wr * 64 + mi * 16 + m;
        af[mi] = *reinterpret_cast<const fragT*>(&As2[R * 64 + cxm * 8]);
      }
#pragma unroll
      for (int ni = 0; ni < 4; ++ni) {
        int R = wc * 64 + ni * 16 + m;
        bfv[ni] = *reinterpret_cast<const fragT*>(&Bs2[R * 64 + cxm * 8]);
      }
      __builtin_amdgcn_s_setprio(1);
#pragma unroll
      for (int mi = 0; mi < 4; ++mi)
#pragma unroll
        for (int ni = 0; ni < 4; ++ni)
          acc[mi][ni] = __builtin_amdgcn_mfma_f32_16x16x32_bf16(af[mi], bfv[ni], acc[mi][ni], 0, 0, 0);
      __builtin_amdgcn_s_setprio(0);
    }
  }

  // ---- epilogue ----
  if (y == 0) {
#pragma unroll
    for (int mi = 0; mi < 4; ++mi)
#pragma unroll
      for (int ni = 0; ni < 4; ++ni) {
        int n = wc * 64 + ni * 16 + m;
        if (n < 96) {
#pragma unroll
          for (int r = 0; r < 4; ++r) {
            int token = row0 + wr * 64 + mi * 16 + g * 4 + r;
            qkb[(size_t)token * 96 + n] = __float2bfloat16(acc[mi][ni][r]);
          }
        }
      }
  } else {
#pragma unroll
    for (int mi = 0; mi < 4; ++mi)
#pragma unroll
      for (int ni = 0; ni < 2; ++ni) {
        int c = (y - 1) * 128 + wc * 32 + ni * 16 + m;  // geglu col 0..767
#pragma unroll
        for (int r = 0; r < 4; ++r) {
          int token = row0 + wr * 64 + mi * 16 + g * 4 + r;
          float lin = acc[mi][ni][r];
          float pre = acc[mi][ni + 2][r];
          float z = 0.79788456f * (pre + 0.044715f * pre * pre * pre);
          float gelu = pre * (1.f / (1.f + __expf(-2.f * z)));
          float gval = lin * gelu;
          if (c < 384)
            gl[(size_t)token * DIM + c] = __float2bfloat16(gval);
          else
            gv[(size_t)token * DIM + (c - 384)] = __float2bfloat16(gval);
        }
      }
  }
}

// ---------------- MFMA windowed causal attention (R11) ----------------
#define ATT_P_OFF 0
#define ATT_Q_OFF 8704
#define ATT_K_OFF 13312
#define ATT_S_OFF 31744
#define ATT_V_OFF 8704
#define ATT_SMEM 48640

__global__ __launch_bounds__(256) void attn_mfma_kernel(
    const bf16* __restrict__ qkb, const bf16* __restrict__ gv,
    const float* __restrict__ pos_mult, bf16* __restrict__ ao) {
  __shared__ char smem[ATT_SMEM];
  bf16* P = (bf16*)(smem + ATT_P_OFF);
  bf16* Qs = (bf16*)(smem + ATT_Q_OFF);
  bf16* Ks = (bf16*)(smem + ATT_K_OFF);
  float* Ss = (float*)(smem + ATT_S_OFF);

  int t = threadIdx.x;
  int lane = t & 63;
  int w = t >> 6;
  int batch = blockIdx.x >> 6;
  int q0 = (blockIdx.x & 63) * 32;
  size_t tb = (size_t)batch * S_LEN;
  int jbase = q0 - 96;
  float cmul = log1pf(expf(pos_mult[0]));
  const float rs = 0.14433756729740643f;
  const short8v z8 = (short8v){0, 0, 0, 0, 0, 0, 0, 0};

  {
    int r = t >> 3, c = t & 7;
    short8v v = z8;
    if (c < 6) v = *reinterpret_cast<const short8v*>(qkb + (tb + q0 + r) * 96 + c * 8);
    *reinterpret_cast<short8v*>(Qs + r * LDAP + c * 8) = v;
  }
  {
    int r = t >> 1, h = t & 1;
    int j = jbase + r;
    if (j >= 0) {
      const bf16* krow = qkb + (tb + j) * 96 + 48 + h * 24;
      *reinterpret_cast<short8v*>(Ks + r * LDAP + h * 24) = *reinterpret_cast<const short8v*>(krow);
      *reinterpret_cast<short8v*>(Ks + r * LDAP + h * 24 + 8) = *reinterpret_cast<const short8v*>(krow + 8);
      *reinterpret_cast<short8v*>(Ks + r * LDAP + h * 24 + 16) = *reinterpret_cast<const short8v*>(krow + 16);
    } else {
      *reinterpret_cast<short8v*>(Ks + r * LDAP + h * 24) = z8;
      *reinterpret_cast<short8v*>(Ks + r * LDAP + h * 24 + 8) = z8;
      *reinterpret_cast<short8v*>(Ks + r * LDAP + h * 24 + 16) = z8;
    }
    if (h == 1) {
      *reinterpret_cast<short8v*>(Ks + r * LDAP + 48) = z8;
      *reinterpret_cast<short8v*>(Ks + r * LDAP + 56) = z8;
    }
  }
  __syncthreads();

  int m = lane & 15, g = lane >> 4;

  {
    f32x4 sacc[2][2];
#pragma unroll
    for (int mi = 0; mi < 2; ++mi)
#pragma unroll
      for (int ni = 0; ni < 2; ++ni) sacc[mi][ni] = (f32x4){0.f, 0.f, 0.f, 0.f};
#pragma unroll
    for (int ks = 0; ks < 2; ++ks) {
      int ko = ks * 32 + g * 8;
      fragT aq[2], bk[2];
#pragma unroll
      for (int mi = 0; mi < 2; ++mi)
        aq[mi] = *reinterpret_cast<const fragT*>(Qs + (mi * 16 + m) * LDAP + ko);
#pragma unroll
      for (int ni = 0; ni < 2; ++ni)
        bk[ni] = *reinterpret_cast<const fragT*>(Ks + (w * 32 + ni * 16 + m) * LDAP + ko);
#pragma unroll
      for (int mi = 0; mi < 2; ++mi)
#pragma unroll
        for (int ni = 0; ni < 2; ++ni)
          sacc[mi][ni] = __builtin_amdgcn_mfma_f32_16x16x32_bf16(aq[mi], bk[ni], sacc[mi][ni], 0, 0, 0);
    }
#pragma unroll
    for (int mi = 0; mi < 2; ++mi)
#pragma unroll
      for (int ni = 0; ni < 2; ++ni)
#pragma unroll
        for (int r = 0; r < 4; ++r) {
          int q = mi * 16 + g * 4 + r;
          int key = w * 32 + ni * 16 + m;
          int gi = q0 + q, gj = jbase + key;
          float s = (gj >= 0 && gj <= gi)
                        ? sacc[mi][ni][r] * rs + cmul * (float)(gj - gi)
                        : -INFINITY;
          Ss[q * 132 + key] = s;
        }
  }
  __syncthreads();

  auto loadVreg = [&](int c, short8v* vreg) {
    int j = t >> 3, c8 = t & 7;
    int gj = jbase + c * 32 + j;
    const bf16* vrow = gv + (tb + gj) * (size_t)DIM;
#pragma unroll
    for (int it = 0; it < 6; ++it) {
      int d = (c8 + it * 8) * 8;
      vreg[it] = (gj >= 0) ? *reinterpret_cast<const short8v*>(vrow + d) : z8;
    }
  };
  auto writeV = [&](const short8v* vreg) {
    int j = t >> 3, c8 = t & 7;
    bf16* vb = (bf16*)(smem + ATT_V_OFF);
#pragma unroll
    for (int it = 0; it < 6; ++it) {
      int d = (c8 + it * 8) * 8;
      *reinterpret_cast<short8v*>(vb + ((j >> 2) * 24 + (d >> 4)) * LDAP + (j & 3) * 16 + (d & 15)) = vreg[it];
    }
  };

  {
    int sq = t >> 3, sl = t & 7;
    union { float4 f4[4]; float f[16]; } su;
#pragma unroll
    for (int u2 = 0; u2 < 4; ++u2)
      su.f4[u2] = *reinterpret_cast<const float4*>(Ss + sq * 132 + sl * 16 + u2 * 4);
    __syncthreads();
    float mx = -INFINITY;
#pragma unroll
    for (int e = 0; e < 16; ++e) mx = fmaxf(mx, su.f[e]);
    mx = fmaxf(mx, __shfl_xor(mx, 1));
    mx = fmaxf(mx, __shfl_xor(mx, 2));
    mx = fmaxf(mx, __shfl_xor(mx, 4));
    float pv[16];
    float sum = 0.f;
#pragma unroll
    for (int e = 0; e < 16; ++e) {
      pv[e] = expf(su.f[e] - mx);
      sum += pv[e];
    }
    sum += __shfl_xor(sum, 1);
    sum += __shfl_xor(sum, 2);
    sum += __shfl_xor(sum, 4);
    float inv = 1.f / sum;
    union { bf16 b[16]; short8v s[2]; } pk;
#pragma unroll
    for (int e = 0; e < 16; ++e) pk.b[e] = __float2bfloat16(pv[e] * inv);
    bf16* pr = P + sq * 136 + sl * 16;
    *reinterpret_cast<short8v*>(pr) = pk.s[0];
    *reinterpret_cast<short8v*>(pr + 8) = pk.s[1];
  }
  {
    short8v v0[6];
    loadVreg(0, v0);
    writeV(v0);
  }
  __syncthreads();

  f32x4 oacc[2][6];
#pragma unroll
  for (int mi = 0; mi < 2; ++mi)
#pragma unroll
    for (int nt = 0; nt < 6; ++nt) oacc[mi][nt] = (f32x4){0.f, 0.f, 0.f, 0.f};

  unsigned sbase = (unsigned)(size_t)(&smem[0]);
  unsigned lanebase = (unsigned)(((48 * g + 6 * w) * LDAP + m) * 2);

  for (int c = 0; c < 4; ++c) {
    short8v vnext[6];
    if (c < 3) loadVreg(c + 1, vnext);
    unsigned vaddr = sbase + ATT_V_OFF + lanebase;
    fragT pa0 = *reinterpret_cast<const fragT*>(P + m * 136 + c * 32 + g * 8);
    fragT pa1 = *reinterpret_cast<const fragT*>(P + (16 + m) * 136 + c * 32 + g * 8);
    uint2v trr[12];
#pragma unroll
    for (int nt = 0; nt < 6; ++nt) {
      asm volatile("ds_read_b64_tr_b16 %0, %1" : "=v"(trr[2 * nt]) : "v"(vaddr + nt * 144));
      asm volatile("ds_read_b64_tr_b16 %0, %1" : "=v"(trr[2 * nt + 1]) : "v"(vaddr + nt * 144 + 3456));
    }
    asm volatile("s_waitcnt lgkmcnt(0)" ::: "memory");
    __builtin_amdgcn_sched_barrier(0);
#pragma unroll
    for (int nt = 0; nt < 6; ++nt) {
      union { int4v i4; fragT f; } u2;
      u2.i4 = (int4v){(int)trr[2 * nt].x, (int)trr[2 * nt].y,
                      (int)trr[2 * nt + 1].x, (int)trr[2 * nt + 1].y};
      oacc[0][nt] = __builtin_amdgcn_mfma_f32_16x16x32_bf16(pa0, u2.f, oacc[0][nt], 0, 0, 0);
      oacc[1][nt] = __builtin_amdgcn_mfma_f32_16x16x32_bf16(pa1, u2.f, oacc[1][nt], 0, 0, 0);
    }
    __syncthreads();
    if (c < 3) {
      writeV(vnext);
      __syncthreads();
    }
  }

#pragma unroll
  for (int mi = 0; mi < 2; ++mi)
#pragma unroll
    for (int nt = 0; nt < 6; ++nt) {
#pragma unroll
      for (int r = 0; r < 4; ++r) {
        int q = mi * 16 + g * 4 + r;
        int d = w * 96 + nt * 16 + m;
        ao[(tb + q0 + q) * (size_t)DIM + d] = __float2bfloat16(oacc[mi][nt][r]);
      }
    }
}

// ---------------- project GEMM: gload_lds staging + residual (R8) ----------
__global__ __launch_bounds__(256, 4) void project_gl_kernel(
    const bf16* __restrict__ gl, const bf16* __restrict__ at,
    const bf16* __restrict__ wpb, const float* __restrict__ x,
    float* __restrict__ out) {
  __shared__ short As2[128 * 64];  // 16384 B
  __shared__ short Bs2[128 * 64];  // 16384 B
  int t = threadIdx.x;
  int bid = blockIdx.x;
  int logical = (bid & 7) * 192 + (bid >> 3);
  int row0 = (logical / 3) * 128;
  int col0 = (logical % 3) * 128;
  int lane = t & 63, w = t >> 6;
  int wr = w >> 1, wc = w & 1;
  int m = lane & 15, g = lane >> 4;

  int lr = lane >> 3;
  int s8 = lane & 7;
  int cs = s8 ^ lr;

  size_t aoff[4];
  const bf16* gbp[4];
#pragma unroll
  for (int i = 0; i < 4; ++i) {
    int row = w * 32 + i * 8 + lr;
    aoff[i] = (size_t)(row0 + row) * 384 + cs * 8;
    gbp[i] = wpb + (size_t)(col0 + row) * 768 + cs * 8;
  }
  short* la[4];
  short* lb[4];
#pragma unroll
  for (int i = 0; i < 4; ++i) {
    la[i] = As2 + (w * 4 + i) * 512;
    lb[i] = Bs2 + (w * 4 + i) * 512;
  }

  f32x4 acc[4][4];
#pragma unroll
  for (int i = 0; i < 4; ++i)
#pragma unroll
    for (int j = 0; j < 4; ++j) acc[i][j] = (f32x4){0.f, 0.f, 0.f, 0.f};

#pragma unroll
  for (int kt = 0; kt < 12; ++kt) {
    const bf16* ab = (kt < 6) ? gl : at;
    int kk = (kt < 6 ? kt : kt - 6) * 64;
    __syncthreads();
#pragma unroll
    for (int i = 0; i < 4; ++i) gl16(ab + aoff[i] + kk, la[i]);
#pragma unroll
    for (int i = 0; i < 4; ++i) gl16(gbp[i] + kt * 64, lb[i]);
    __syncthreads();
#pragma unroll
    for (int ks = 0; ks < 2; ++ks) {
      int c = ks * 4 + g;
      int cxm = c ^ (m & 7);
      fragT af[4], bfv[4];
#pragma unroll
      for (int mi = 0; mi < 4; ++mi) {
        int R = wr * 64 + mi * 16 + m;
        af[mi] = *reinterpret_cast<const fragT*>(&As2[R * 64 + cxm * 8]);
      }
#pragma unroll
      for (int ni = 0; ni < 4; ++ni) {
        int R = wc * 64 + ni * 16 + m;
        bfv[ni] = *reinterpret_cast<const fragT*>(&Bs2[R * 64 + cxm * 8]);
      }
      __builtin_amdgcn_s_setprio(1);
#pragma unroll
      for (int mi = 0; mi < 4; ++mi)
#pragma unroll
        for (int ni = 0; ni < 4; ++ni)
          acc[mi][ni] = __builtin_amdgcn_mfma_f32_16x16x32_bf16(af[mi], bfv[ni], acc[mi][ni], 0, 0, 0);
      __builtin_amdgcn_s_setprio(0);
    }
  }

#pragma unroll
  for (int mi = 0; mi < 4; ++mi)
#pragma unroll
    for (int ni = 0; ni < 4; ++ni) {
      int d = col0 + wc * 64 + ni * 16 + m;
#pragma unroll
      for (int r = 0; r < 4; ++r) {
        int token = row0 + wr * 64 + mi * 16 + g * 4 + r;
        out[(size_t)token * DIM + d] = x[(size_t)token * DIM + d] + acc[mi][ni][r];
      }
    }
}

extern "C" void kernel_launch(void* const* d_in, const int* in_sizes, int n_in,
                              void* d_out, int out_size, void* d_ws, size_t ws_size,
                              hipStream_t stream) {
  (void)in_sizes; (void)n_in; (void)out_size; (void)ws_size;
  const float* x = (const float*)d_in[0];
  const float* nw = (const float*)d_in[1];
  const float* we = (const float*)d_in[2];
  const float* wp = (const float*)d_in[3];
  const float* pm = (const float*)d_in[4];
  char* ws = (char*)d_ws;
  bf16* xn = (bf16*)(ws);
  bf16* qk = (bf16*)(ws + 50331648);
  bf16* gl = (bf16*)(ws + 62914560);
  bf16* gv = (bf16*)(ws + 113246208);
  bf16* at = (bf16*)(ws + 163577856);
  bf16* web = (bf16*)(ws + 163577856);  // alias: consumed before `at` is written
  bf16* wpb = (bf16*)(ws + 213909504);
  float* out = (float*)d_out;

  hipLaunchKernelGGL(conv_kernel, dim3(512), dim3(256), 0, stream, we, wp, web, wpb);
  hipLaunchKernelGGL(ln_kernel, dim3(NTOK / 4), dim3(256), 0, stream, x, nw, xn);
  hipLaunchKernelGGL(expand_gl_kernel, dim3(512 * 7), dim3(512), 0, stream, xn, web, qk, gl, gv);
  hipLaunchKernelGGL(attn_mfma_kernel, dim3(NBATCH * (S_LEN / 32)), dim3(256), 0, stream, qk, gv, pm, at);
  hipLaunchKernelGGL(project_gl_kernel, dim3(512 * 3), dim3(256), 0, stream, gl, at, wpb, x, out);
}

// Round 13
// 748.820 us; speedup vs baseline: 1.5459x; 1.5459x over previous
//
#include <hip/hip_runtime.h>
#include <hip/hip_bf16.h>
#include <math.h>

#define S_LEN 2048
#define NBATCH 32
#define DIM 384
#define NTOK (NBATCH * S_LEN)

typedef __hip_bfloat16 bf16;
typedef __attribute__((ext_vector_type(8))) short short8v;
typedef __attribute__((ext_vector_type(4))) float f32x4;
typedef __attribute__((ext_vector_type(2))) unsigned int uint2v;
typedef __attribute__((ext_vector_type(4))) int int4v;
typedef short8v fragT;

#define LDAP 72  // padded LDS leading dim (halfwords) — attn kernel only

__device__ __forceinline__ float bf2f(unsigned short u) {
  union { unsigned int i; float f; } c; c.i = ((unsigned int)u) << 16; return c.f;
}

// direct global->LDS DMA, 16B per lane; LDS dest = wave-uniform base + lane*16
__device__ __forceinline__ void gl16(const bf16* g, short* l) {
  __builtin_amdgcn_global_load_lds(
      (const __attribute__((address_space(1))) void*)g,
      (__attribute__((address_space(3))) void*)l, 16, 0, 0);
}

// ---------------- weight fp32 -> bf16 conversion ----------------
__global__ __launch_bounds__(256) void conv_kernel(const float* __restrict__ we,
                                                   const float* __restrict__ wp,
                                                   bf16* __restrict__ web,
                                                   bf16* __restrict__ wpb) {
  int i = blockIdx.x * 256 + threadIdx.x;
  int stride = gridDim.x * 256;
  for (int j = i; j < 1632 * 384; j += stride) web[j] = __float2bfloat16(we[j]);
  for (int j = i; j < 384 * 768; j += stride) wpb[j] = __float2bfloat16(wp[j]);
}

// ---------------- LayerNorm: x (fp32) -> xn (bf16) ----------------
__global__ __launch_bounds__(256) void ln_kernel(const float* __restrict__ x,
                                                 const float* __restrict__ nw,
                                                 bf16* __restrict__ xn) {
  int token = blockIdx.x * 4 + (threadIdx.x >> 6);
  int lane = threadIdx.x & 63;
  const float* xr = x + (size_t)token * DIM;
  float v[6];
  float s = 0.f, sq = 0.f;
#pragma unroll
  for (int j = 0; j < 6; ++j) {
    v[j] = xr[lane + j * 64];
    s += v[j];
    sq += v[j] * v[j];
  }
#pragma unroll
  for (int o = 32; o; o >>= 1) {
    s += __shfl_xor(s, o);
    sq += __shfl_xor(sq, o);
  }
  float mu = s * (1.f / DIM);
  float var = sq * (1.f / DIM) - mu * mu;
  float rs = rsqrtf(var + 1e-5f);
  bf16* xo = xn + (size_t)token * DIM;
#pragma unroll
  for (int j = 0; j < 6; ++j) {
    int c = lane + j * 64;
    xo[c] = __float2bfloat16((v[j] - mu) * rs * nw[c]);
  }
}

// ---------------- expand GEMM: gload_lds staging, 5 blocks/CU --------------
// BM=128 x BN=128, BK=64, 6 K-steps, 4 waves (2M x 2N), 32 KB LDS single buf,
// 2 barriers/step. Linear LDS + pre-swizzled source (chunk ^= row&7).
// Grid 6656 = 512 x * 13 y, XCD-swizzled y-inner (A-tile L2-hot).
// launch_bounds(256,5): 5 blocks x 32KB = 160KB LDS exactly; VGPR cap 409>64.
__global__ __launch_bounds__(256, 5) void expand_gl_kernel(
    const bf16* __restrict__ xn, const bf16* __restrict__ web,
    bf16* __restrict__ qkb, bf16* __restrict__ gl, bf16* __restrict__ gv) {
  __shared__ short As2[128 * 64];  // 16384 B, linear
  __shared__ short Bs2[128 * 64];  // 16384 B, linear
  int t = threadIdx.x;
  int lane = t & 63, w = t >> 6;
  int wr = w >> 1, wc = w & 1;
  int m = lane & 15, g = lane >> 4;

  int bid = blockIdx.x;
  int logical = (bid & 7) * 832 + (bid >> 3);
  int xt = logical / 13, y = logical % 13;
  int row0 = xt * 128;

  int lr = lane >> 3;      // row within 8-row group
  int s8 = lane & 7;       // LDS slot this lane fills
  int cs = s8 ^ lr;        // swizzled source chunk

  const bf16* ga[4];
  const bf16* gb[4];
#pragma unroll
  for (int i = 0; i < 4; ++i) {
    int row = w * 32 + i * 8 + lr;
    ga[i] = xn + (size_t)(row0 + row) * 384 + cs * 8;
    int brow;
    if (y == 0) brow = (row < 96) ? row : 95;  // clamp: harmless garbage
    else {
      int q = row >> 5, nn = row & 31;
      int base = (y - 1) * 64 + (q >> 1) * 32 + nn;
      brow = (q & 1) ? (864 + base) : (96 + base);
    }
    gb[i] = web + (size_t)brow * 384 + cs * 8;
  }
  short* la[4];
  short* lb[4];
#pragma unroll
  for (int i = 0; i < 4; ++i) {
    la[i] = As2 + (w * 4 + i) * 512;
    lb[i] = Bs2 + (w * 4 + i) * 512;
  }

  f32x4 acc[4][4];
#pragma unroll
  for (int i = 0; i < 4; ++i)
#pragma unroll
    for (int j = 0; j < 4; ++j) acc[i][j] = (f32x4){0.f, 0.f, 0.f, 0.f};

#pragma unroll
  for (int kt = 0; kt < 6; ++kt) {
    __syncthreads();  // prior step's ds_reads done before overwrite
#pragma unroll
    for (int i = 0; i < 4; ++i) gl16(ga[i] + kt * 64, la[i]);
#pragma unroll
    for (int i = 0; i < 4; ++i) gl16(gb[i] + kt * 64, lb[i]);
    __syncthreads();  // vmcnt(0) drained before barrier -> LDS valid
#pragma unroll
    for (int ks = 0; ks < 2; ++ks) {
      int c = ks * 4 + g;
      int cxm = c ^ (m & 7);
      fragT af[4], bfv[4];
#pragma unroll
      for (int mi = 0; mi < 4; ++mi) {
        int R = wr * 64 + mi * 16 + m;
        af[mi] = *reinterpret_cast<const fragT*>(&As2[R * 64 + cxm * 8]);
      }
#pragma unroll
      for (int ni = 0; ni < 4; ++ni) {
        int R = wc * 64 + ni * 16 + m;
        bfv[ni] = *reinterpret_cast<const fragT*>(&Bs2[R * 64 + cxm * 8]);
      }
      __builtin_amdgcn_s_setprio(1);
#pragma unroll
      for (int mi = 0; mi < 4; ++mi)
#pragma unroll
        for (int ni = 0; ni < 4; ++ni)
          acc[mi][ni] = __builtin_amdgcn_mfma_f32_16x16x32_bf16(af[mi], bfv[ni], acc[mi][ni], 0, 0, 0);
      __builtin_amdgcn_s_setprio(0);
    }
  }

  // ---- epilogue ----
  if (y == 0) {
#pragma unroll
    for (int mi = 0; mi < 4; ++mi)
#pragma unroll
      for (int ni = 0; ni < 4; ++ni) {
        int n = wc * 64 + ni * 16 + m;
        if (n < 96) {
#pragma unroll
          for (int r = 0; r < 4; ++r) {
            int token = row0 + wr * 64 + mi * 16 + g * 4 + r;
            qkb[(size_t)token * 96 + n] = __float2bfloat16(acc[mi][ni][r]);
          }
        }
      }
  } else {
#pragma unroll
    for (int mi = 0; mi < 4; ++mi)
#pragma unroll
      for (int ni = 0; ni < 2; ++ni) {
        int c = (y - 1) * 64 + wc * 32 + ni * 16 + m;  // geglu col 0..767
#pragma unroll
        for (int r = 0; r < 4; ++r) {
          int token = row0 + wr * 64 + mi * 16 + g * 4 + r;
          float lin = acc[mi][ni][r];
          float pre = acc[mi][ni + 2][r];
          float z = 0.79788456f * (pre + 0.044715f * pre * pre * pre);
          float gelu = pre * (1.f / (1.f + __expf(-2.f * z)));
          float gval = lin * gelu;
          if (c < 384)
            gl[(size_t)token * DIM + c] = __float2bfloat16(gval);
          else
            gv[(size_t)token * DIM + (c - 384)] = __float2bfloat16(gval);
        }
      }
  }
}

// ---------------- MFMA windowed causal attention (R11) ----------------
#define ATT_P_OFF 0
#define ATT_Q_OFF 8704
#define ATT_K_OFF 13312
#define ATT_S_OFF 31744
#define ATT_V_OFF 8704
#define ATT_SMEM 48640

__global__ __launch_bounds__(256) void attn_mfma_kernel(
    const bf16* __restrict__ qkb, const bf16* __restrict__ gv,
    const float* __restrict__ pos_mult, bf16* __restrict__ ao) {
  __shared__ char smem[ATT_SMEM];
  bf16* P = (bf16*)(smem + ATT_P_OFF);
  bf16* Qs = (bf16*)(smem + ATT_Q_OFF);
  bf16* Ks = (bf16*)(smem + ATT_K_OFF);
  float* Ss = (float*)(smem + ATT_S_OFF);

  int t = threadIdx.x;
  int lane = t & 63;
  int w = t >> 6;
  int batch = blockIdx.x >> 6;
  int q0 = (blockIdx.x & 63) * 32;
  size_t tb = (size_t)batch * S_LEN;
  int jbase = q0 - 96;
  float cmul = log1pf(expf(pos_mult[0]));
  const float rs = 0.14433756729740643f;
  const short8v z8 = (short8v){0, 0, 0, 0, 0, 0, 0, 0};

  {
    int r = t >> 3, c = t & 7;
    short8v v = z8;
    if (c < 6) v = *reinterpret_cast<const short8v*>(qkb + (tb + q0 + r) * 96 + c * 8);
    *reinterpret_cast<short8v*>(Qs + r * LDAP + c * 8) = v;
  }
  {
    int r = t >> 1, h = t & 1;
    int j = jbase + r;
    if (j >= 0) {
      const bf16* krow = qkb + (tb + j) * 96 + 48 + h * 24;
      *reinterpret_cast<short8v*>(Ks + r * LDAP + h * 24) = *reinterpret_cast<const short8v*>(krow);
      *reinterpret_cast<short8v*>(Ks + r * LDAP + h * 24 + 8) = *reinterpret_cast<const short8v*>(krow + 8);
      *reinterpret_cast<short8v*>(Ks + r * LDAP + h * 24 + 16) = *reinterpret_cast<const short8v*>(krow + 16);
    } else {
      *reinterpret_cast<short8v*>(Ks + r * LDAP + h * 24) = z8;
      *reinterpret_cast<short8v*>(Ks + r * LDAP + h * 24 + 8) = z8;
      *reinterpret_cast<short8v*>(Ks + r * LDAP + h * 24 + 16) = z8;
    }
    if (h == 1) {
      *reinterpret_cast<short8v*>(Ks + r * LDAP + 48) = z8;
      *reinterpret_cast<short8v*>(Ks + r * LDAP + 56) = z8;
    }
  }
  __syncthreads();

  int m = lane & 15, g = lane >> 4;

  {
    f32x4 sacc[2][2];
#pragma unroll
    for (int mi = 0; mi < 2; ++mi)
#pragma unroll
      for (int ni = 0; ni < 2; ++ni) sacc[mi][ni] = (f32x4){0.f, 0.f, 0.f, 0.f};
#pragma unroll
    for (int ks = 0; ks < 2; ++ks) {
      int ko = ks * 32 + g * 8;
      fragT aq[2], bk[2];
#pragma unroll
      for (int mi = 0; mi < 2; ++mi)
        aq[mi] = *reinterpret_cast<const fragT*>(Qs + (mi * 16 + m) * LDAP + ko);
#pragma unroll
      for (int ni = 0; ni < 2; ++ni)
        bk[ni] = *reinterpret_cast<const fragT*>(Ks + (w * 32 + ni * 16 + m) * LDAP + ko);
#pragma unroll
      for (int mi = 0; mi < 2; ++mi)
#pragma unroll
        for (int ni = 0; ni < 2; ++ni)
          sacc[mi][ni] = __builtin_amdgcn_mfma_f32_16x16x32_bf16(aq[mi], bk[ni], sacc[mi][ni], 0, 0, 0);
    }
#pragma unroll
    for (int mi = 0; mi < 2; ++mi)
#pragma unroll
      for (int ni = 0; ni < 2; ++ni)
#pragma unroll
        for (int r = 0; r < 4; ++r) {
          int q = mi * 16 + g * 4 + r;
          int key = w * 32 + ni * 16 + m;
          int gi = q0 + q, gj = jbase + key;
          float s = (gj >= 0 && gj <= gi)
                        ? sacc[mi][ni][r] * rs + cmul * (float)(gj - gi)
                        : -INFINITY;
          Ss[q * 132 + key] = s;
        }
  }
  __syncthreads();

  auto loadVreg = [&](int c, short8v* vreg) {
    int j = t >> 3, c8 = t & 7;
    int gj = jbase + c * 32 + j;
    const bf16* vrow = gv + (tb + gj) * (size_t)DIM;
#pragma unroll
    for (int it = 0; it < 6; ++it) {
      int d = (c8 + it * 8) * 8;
      vreg[it] = (gj >= 0) ? *reinterpret_cast<const short8v*>(vrow + d) : z8;
    }
  };
  auto writeV = [&](const short8v* vreg) {
    int j = t >> 3, c8 = t & 7;
    bf16* vb = (bf16*)(smem + ATT_V_OFF);
#pragma unroll
    for (int it = 0; it < 6; ++it) {
      int d = (c8 + it * 8) * 8;
      *reinterpret_cast<short8v*>(vb + ((j >> 2) * 24 + (d >> 4)) * LDAP + (j & 3) * 16 + (d & 15)) = vreg[it];
    }
  };

  {
    int sq = t >> 3, sl = t & 7;
    union { float4 f4[4]; float f[16]; } su;
#pragma unroll
    for (int u2 = 0; u2 < 4; ++u2)
      su.f4[u2] = *reinterpret_cast<const float4*>(Ss + sq * 132 + sl * 16 + u2 * 4);
    __syncthreads();
    float mx = -INFINITY;
#pragma unroll
    for (int e = 0; e < 16; ++e) mx = fmaxf(mx, su.f[e]);
    mx = fmaxf(mx, __shfl_xor(mx, 1));
    mx = fmaxf(mx, __shfl_xor(mx, 2));
    mx = fmaxf(mx, __shfl_xor(mx, 4));
    float pv[16];
    float sum = 0.f;
#pragma unroll
    for (int e = 0; e < 16; ++e) {
      pv[e] = expf(su.f[e] - mx);
      sum += pv[e];
    }
    sum += __shfl_xor(sum, 1);
    sum += __shfl_xor(sum, 2);
    sum += __shfl_xor(sum, 4);
    float inv = 1.f / sum;
    union { bf16 b[16]; short8v s[2]; } pk;
#pragma unroll
    for (int e = 0; e < 16; ++e) pk.b[e] = __float2bfloat16(pv[e] * inv);
    bf16* pr = P + sq * 136 + sl * 16;
    *reinterpret_cast<short8v*>(pr) = pk.s[0];
    *reinterpret_cast<short8v*>(pr + 8) = pk.s[1];
  }
  {
    short8v v0[6];
    loadVreg(0, v0);
    writeV(v0);
  }
  __syncthreads();

  f32x4 oacc[2][6];
#pragma unroll
  for (int mi = 0; mi < 2; ++mi)
#pragma unroll
    for (int nt = 0; nt < 6; ++nt) oacc[mi][nt] = (f32x4){0.f, 0.f, 0.f, 0.f};

  unsigned sbase = (unsigned)(size_t)(&smem[0]);
  unsigned lanebase = (unsigned)(((48 * g + 6 * w) * LDAP + m) * 2);

  for (int c = 0; c < 4; ++c) {
    short8v vnext[6];
    if (c < 3) loadVreg(c + 1, vnext);
    unsigned vaddr = sbase + ATT_V_OFF + lanebase;
    fragT pa0 = *reinterpret_cast<const fragT*>(P + m * 136 + c * 32 + g * 8);
    fragT pa1 = *reinterpret_cast<const fragT*>(P + (16 + m) * 136 + c * 32 + g * 8);
    uint2v trr[12];
#pragma unroll
    for (int nt = 0; nt < 6; ++nt) {
      asm volatile("ds_read_b64_tr_b16 %0, %1" : "=v"(trr[2 * nt]) : "v"(vaddr + nt * 144));
      asm volatile("ds_read_b64_tr_b16 %0, %1" : "=v"(trr[2 * nt + 1]) : "v"(vaddr + nt * 144 + 3456));
    }
    asm volatile("s_waitcnt lgkmcnt(0)" ::: "memory");
    __builtin_amdgcn_sched_barrier(0);
#pragma unroll
    for (int nt = 0; nt < 6; ++nt) {
      union { int4v i4; fragT f; } u2;
      u2.i4 = (int4v){(int)trr[2 * nt].x, (int)trr[2 * nt].y,
                      (int)trr[2 * nt + 1].x, (int)trr[2 * nt + 1].y};
      oacc[0][nt] = __builtin_amdgcn_mfma_f32_16x16x32_bf16(pa0, u2.f, oacc[0][nt], 0, 0, 0);
      oacc[1][nt] = __builtin_amdgcn_mfma_f32_16x16x32_bf16(pa1, u2.f, oacc[1][nt], 0, 0, 0);
    }
    __syncthreads();
    if (c < 3) {
      writeV(vnext);
      __syncthreads();
    }
  }

#pragma unroll
  for (int mi = 0; mi < 2; ++mi)
#pragma unroll
    for (int nt = 0; nt < 6; ++nt) {
#pragma unroll
      for (int r = 0; r < 4; ++r) {
        int q = mi * 16 + g * 4 + r;
        int d = w * 96 + nt * 16 + m;
        ao[(tb + q0 + q) * (size_t)DIM + d] = __float2bfloat16(oacc[mi][nt][r]);
      }
    }
}

// ---------------- project GEMM: gload_lds staging + residual, 5 blocks/CU --
__global__ __launch_bounds__(256, 5) void project_gl_kernel(
    const bf16* __restrict__ gl, const bf16* __restrict__ at,
    const bf16* __restrict__ wpb, const float* __restrict__ x,
    float* __restrict__ out) {
  __shared__ short As2[128 * 64];  // 16384 B
  __shared__ short Bs2[128 * 64];  // 16384 B
  int t = threadIdx.x;
  int bid = blockIdx.x;
  int logical = (bid & 7) * 192 + (bid >> 3);
  int row0 = (logical / 3) * 128;
  int col0 = (logical % 3) * 128;
  int lane = t & 63, w = t >> 6;
  int wr = w >> 1, wc = w & 1;
  int m = lane & 15, g = lane >> 4;

  int lr = lane >> 3;
  int s8 = lane & 7;
  int cs = s8 ^ lr;

  size_t aoff[4];
  const bf16* gbp[4];
#pragma unroll
  for (int i = 0; i < 4; ++i) {
    int row = w * 32 + i * 8 + lr;
    aoff[i] = (size_t)(row0 + row) * 384 + cs * 8;
    gbp[i] = wpb + (size_t)(col0 + row) * 768 + cs * 8;
  }
  short* la[4];
  short* lb[4];
#pragma unroll
  for (int i = 0; i < 4; ++i) {
    la[i] = As2 + (w * 4 + i) * 512;
    lb[i] = Bs2 + (w * 4 + i) * 512;
  }

  f32x4 acc[4][4];
#pragma unroll
  for (int i = 0; i < 4; ++i)
#pragma unroll
    for (int j = 0; j < 4; ++j) acc[i][j] = (f32x4){0.f, 0.f, 0.f, 0.f};

#pragma unroll
  for (int kt = 0; kt < 12; ++kt) {
    const bf16* ab = (kt < 6) ? gl : at;
    int kk = (kt < 6 ? kt : kt - 6) * 64;
    __syncthreads();
#pragma unroll
    for (int i = 0; i < 4; ++i) gl16(ab + aoff[i] + kk, la[i]);
#pragma unroll
    for (int i = 0; i < 4; ++i) gl16(gbp[i] + kt * 64, lb[i]);
    __syncthreads();
#pragma unroll
    for (int ks = 0; ks < 2; ++ks) {
      int c = ks * 4 + g;
      int cxm = c ^ (m & 7);
      fragT af[4], bfv[4];
#pragma unroll
      for (int mi = 0; mi < 4; ++mi) {
        int R = wr * 64 + mi * 16 + m;
        af[mi] = *reinterpret_cast<const fragT*>(&As2[R * 64 + cxm * 8]);
      }
#pragma unroll
      for (int ni = 0; ni < 4; ++ni) {
        int R = wc * 64 + ni * 16 + m;
        bfv[ni] = *reinterpret_cast<const fragT*>(&Bs2[R * 64 + cxm * 8]);
      }
      __builtin_amdgcn_s_setprio(1);
#pragma unroll
      for (int mi = 0; mi < 4; ++mi)
#pragma unroll
        for (int ni = 0; ni < 4; ++ni)
          acc[mi][ni] = __builtin_amdgcn_mfma_f32_16x16x32_bf16(af[mi], bfv[ni], acc[mi][ni], 0, 0, 0);
      __builtin_amdgcn_s_setprio(0);
    }
  }

#pragma unroll
  for (int mi = 0; mi < 4; ++mi)
#pragma unroll
    for (int ni = 0; ni < 4; ++ni) {
      int d = col0 + wc * 64 + ni * 16 + m;
#pragma unroll
      for (int r = 0; r < 4; ++r) {
        int token = row0 + wr * 64 + mi * 16 + g * 4 + r;
        out[(size_t)token * DIM + d] = x[(size_t)token * DIM + d] + acc[mi][ni][r];
      }
    }
}

extern "C" void kernel_launch(void* const* d_in, const int* in_sizes, int n_in,
                              void* d_out, int out_size, void* d_ws, size_t ws_size,
                              hipStream_t stream) {
  (void)in_sizes; (void)n_in; (void)out_size; (void)ws_size;
  const float* x = (const float*)d_in[0];
  const float* nw = (const float*)d_in[1];
  const float* we = (const float*)d_in[2];
  const float* wp = (const float*)d_in[3];
  const float* pm = (const float*)d_in[4];
  char* ws = (char*)d_ws;
  bf16* xn = (bf16*)(ws);
  bf16* qk = (bf16*)(ws + 50331648);
  bf16* gl = (bf16*)(ws + 62914560);
  bf16* gv = (bf16*)(ws + 113246208);
  bf16* at = (bf16*)(ws + 163577856);
  bf16* web = (bf16*)(ws + 163577856);  // alias: consumed before `at` is written
  bf16* wpb = (bf16*)(ws + 213909504);
  float* out = (float*)d_out;

  hipLaunchKernelGGL(conv_kernel, dim3(512), dim3(256), 0, stream, we, wp, web, wpb);
  hipLaunchKernelGGL(ln_kernel, dim3(NTOK / 4), dim3(256), 0, stream, x, nw, xn);
  hipLaunchKernelGGL(expand_gl_kernel, dim3(512 * 13), dim3(256), 0, stream, xn, web, qk, gl, gv);
  hipLaunchKernelGGL(attn_mfma_kernel, dim3(NBATCH * (S_LEN / 32)), dim3(256), 0, stream, qk, gv, pm, at);
  hipLaunchKernelGGL(project_gl_kernel, dim3(512 * 3), dim3(256), 0, stream, gl, at, wpb, x, out);
}

// Round 14
// 248.772 us; speedup vs baseline: 4.6531x; 3.0101x over previous
//
#include <hip/hip_runtime.h>
#include <hip/hip_bf16.h>
#include <math.h>

#define S_LEN 2048
#define NBATCH 32
#define DIM 384
#define NTOK (NBATCH * S_LEN)

typedef __hip_bfloat16 bf16;
typedef __attribute__((ext_vector_type(8))) short short8v;
typedef __attribute__((ext_vector_type(4))) float f32x4;
typedef __attribute__((ext_vector_type(2))) unsigned int uint2v;
typedef __attribute__((ext_vector_type(4))) int int4v;
typedef short8v fragT;

#define LDAP 72  // padded LDS leading dim (halfwords) — attn kernel only

__device__ __forceinline__ float bf2f(unsigned short u) {
  union { unsigned int i; float f; } c; c.i = ((unsigned int)u) << 16; return c.f;
}

// direct global->LDS DMA, 16B per lane; LDS dest = wave-uniform base + lane*16
__device__ __forceinline__ void gl16(const bf16* g, short* l) {
  __builtin_amdgcn_global_load_lds(
      (const __attribute__((address_space(1))) void*)g,
      (__attribute__((address_space(3))) void*)l, 16, 0, 0);
}

// ---------------- weight fp32 -> bf16 conversion ----------------
__global__ __launch_bounds__(256) void conv_kernel(const float* __restrict__ we,
                                                   const float* __restrict__ wp,
                                                   bf16* __restrict__ web,
                                                   bf16* __restrict__ wpb) {
  int i = blockIdx.x * 256 + threadIdx.x;
  int stride = gridDim.x * 256;
  for (int j = i; j < 1632 * 384; j += stride) web[j] = __float2bfloat16(we[j]);
  for (int j = i; j < 384 * 768; j += stride) wpb[j] = __float2bfloat16(wp[j]);
}

// ---------------- LayerNorm: x (fp32) -> xn (bf16) ----------------
__global__ __launch_bounds__(256) void ln_kernel(const float* __restrict__ x,
                                                 const float* __restrict__ nw,
                                                 bf16* __restrict__ xn) {
  int token = blockIdx.x * 4 + (threadIdx.x >> 6);
  int lane = threadIdx.x & 63;
  const float* xr = x + (size_t)token * DIM;
  float v[6];
  float s = 0.f, sq = 0.f;
#pragma unroll
  for (int j = 0; j < 6; ++j) {
    v[j] = xr[lane + j * 64];
    s += v[j];
    sq += v[j] * v[j];
  }
#pragma unroll
  for (int o = 32; o; o >>= 1) {
    s += __shfl_xor(s, o);
    sq += __shfl_xor(sq, o);
  }
  float mu = s * (1.f / DIM);
  float var = sq * (1.f / DIM) - mu * mu;
  float rs = rsqrtf(var + 1e-5f);
  bf16* xo = xn + (size_t)token * DIM;
#pragma unroll
  for (int j = 0; j < 6; ++j) {
    int c = lane + j * 64;
    xo[c] = __float2bfloat16((v[j] - mu) * rs * nw[c]);
  }
}

// ---------------- expand GEMM: gload_lds staging, 4 blocks/CU (R8/R11) -----
// BM=128 x BN=128, BK=64, 6 K-steps, 4 waves (2M x 2N), 32 KB LDS single buf,
// 2 barriers/step. Linear LDS + pre-swizzled source (chunk ^= row&7).
// Grid 6656 = 512 x * 13 y, XCD-swizzled y-inner (A-tile L2-hot).
// NOTE: launch_bounds 2nd arg MUST stay 4 — 5 or 6 clamps VGPR below the
// 64-reg accumulator and spills (R12: 40 regs, R13: 48 regs, both ~4-9x slower).
__global__ __launch_bounds__(256, 4) void expand_gl_kernel(
    const bf16* __restrict__ xn, const bf16* __restrict__ web,
    bf16* __restrict__ qkb, bf16* __restrict__ gl, bf16* __restrict__ gv) {
  __shared__ short As2[128 * 64];  // 16384 B, linear
  __shared__ short Bs2[128 * 64];  // 16384 B, linear
  int t = threadIdx.x;
  int lane = t & 63, w = t >> 6;
  int wr = w >> 1, wc = w & 1;
  int m = lane & 15, g = lane >> 4;

  int bid = blockIdx.x;
  int logical = (bid & 7) * 832 + (bid >> 3);
  int xt = logical / 13, y = logical % 13;
  int row0 = xt * 128;

  int lr = lane >> 3;      // row within 8-row group
  int s8 = lane & 7;       // LDS slot this lane fills
  int cs = s8 ^ lr;        // swizzled source chunk

  const bf16* ga[4];
  const bf16* gb[4];
#pragma unroll
  for (int i = 0; i < 4; ++i) {
    int row = w * 32 + i * 8 + lr;
    ga[i] = xn + (size_t)(row0 + row) * 384 + cs * 8;
    int brow;
    if (y == 0) brow = (row < 96) ? row : 95;  // clamp: harmless garbage
    else {
      int q = row >> 5, nn = row & 31;
      int base = (y - 1) * 64 + (q >> 1) * 32 + nn;
      brow = (q & 1) ? (864 + base) : (96 + base);
    }
    gb[i] = web + (size_t)brow * 384 + cs * 8;
  }
  short* la[4];
  short* lb[4];
#pragma unroll
  for (int i = 0; i < 4; ++i) {
    la[i] = As2 + (w * 4 + i) * 512;
    lb[i] = Bs2 + (w * 4 + i) * 512;
  }

  f32x4 acc[4][4];
#pragma unroll
  for (int i = 0; i < 4; ++i)
#pragma unroll
    for (int j = 0; j < 4; ++j) acc[i][j] = (f32x4){0.f, 0.f, 0.f, 0.f};

#pragma unroll
  for (int kt = 0; kt < 6; ++kt) {
    __syncthreads();  // prior step's ds_reads done before overwrite
#pragma unroll
    for (int i = 0; i < 4; ++i) gl16(ga[i] + kt * 64, la[i]);
#pragma unroll
    for (int i = 0; i < 4; ++i) gl16(gb[i] + kt * 64, lb[i]);
    __syncthreads();  // vmcnt(0) drained before barrier -> LDS valid
#pragma unroll
    for (int ks = 0; ks < 2; ++ks) {
      int c = ks * 4 + g;
      int cxm = c ^ (m & 7);
      fragT af[4], bfv[4];
#pragma unroll
      for (int mi = 0; mi < 4; ++mi) {
        int R = wr * 64 + mi * 16 + m;
        af[mi] = *reinterpret_cast<const fragT*>(&As2[R * 64 + cxm * 8]);
      }
#pragma unroll
      for (int ni = 0; ni < 4; ++ni) {
        int R = wc * 64 + ni * 16 + m;
        bfv[ni] = *reinterpret_cast<const fragT*>(&Bs2[R * 64 + cxm * 8]);
      }
      __builtin_amdgcn_s_setprio(1);
#pragma unroll
      for (int mi = 0; mi < 4; ++mi)
#pragma unroll
        for (int ni = 0; ni < 4; ++ni)
          acc[mi][ni] = __builtin_amdgcn_mfma_f32_16x16x32_bf16(af[mi], bfv[ni], acc[mi][ni], 0, 0, 0);
      __builtin_amdgcn_s_setprio(0);
    }
  }

  // ---- epilogue ----
  if (y == 0) {
#pragma unroll
    for (int mi = 0; mi < 4; ++mi)
#pragma unroll
      for (int ni = 0; ni < 4; ++ni) {
        int n = wc * 64 + ni * 16 + m;
        if (n < 96) {
#pragma unroll
          for (int r = 0; r < 4; ++r) {
            int token = row0 + wr * 64 + mi * 16 + g * 4 + r;
            qkb[(size_t)token * 96 + n] = __float2bfloat16(acc[mi][ni][r]);
          }
        }
      }
  } else {
#pragma unroll
    for (int mi = 0; mi < 4; ++mi)
#pragma unroll
      for (int ni = 0; ni < 2; ++ni) {
        int c = (y - 1) * 64 + wc * 32 + ni * 16 + m;  // geglu col 0..767
#pragma unroll
        for (int r = 0; r < 4; ++r) {
          int token = row0 + wr * 64 + mi * 16 + g * 4 + r;
          float lin = acc[mi][ni][r];
          float pre = acc[mi][ni + 2][r];
          float z = 0.79788456f * (pre + 0.044715f * pre * pre * pre);
          float gelu = pre * (1.f / (1.f + __expf(-2.f * z)));
          float gval = lin * gelu;
          if (c < 384)
            gl[(size_t)token * DIM + c] = __float2bfloat16(gval);
          else
            gv[(size_t)token * DIM + (c - 384)] = __float2bfloat16(gval);
        }
      }
  }
}

// ---------------- MFMA windowed causal attention (R11) ----------------
#define ATT_P_OFF 0
#define ATT_Q_OFF 8704
#define ATT_K_OFF 13312
#define ATT_S_OFF 31744
#define ATT_V_OFF 8704
#define ATT_SMEM 48640

__global__ __launch_bounds__(256) void attn_mfma_kernel(
    const bf16* __restrict__ qkb, const bf16* __restrict__ gv,
    const float* __restrict__ pos_mult, bf16* __restrict__ ao) {
  __shared__ char smem[ATT_SMEM];
  bf16* P = (bf16*)(smem + ATT_P_OFF);
  bf16* Qs = (bf16*)(smem + ATT_Q_OFF);
  bf16* Ks = (bf16*)(smem + ATT_K_OFF);
  float* Ss = (float*)(smem + ATT_S_OFF);

  int t = threadIdx.x;
  int lane = t & 63;
  int w = t >> 6;
  int batch = blockIdx.x >> 6;
  int q0 = (blockIdx.x & 63) * 32;
  size_t tb = (size_t)batch * S_LEN;
  int jbase = q0 - 96;
  float cmul = log1pf(expf(pos_mult[0]));
  const float rs = 0.14433756729740643f;
  const short8v z8 = (short8v){0, 0, 0, 0, 0, 0, 0, 0};

  {
    int r = t >> 3, c = t & 7;
    short8v v = z8;
    if (c < 6) v = *reinterpret_cast<const short8v*>(qkb + (tb + q0 + r) * 96 + c * 8);
    *reinterpret_cast<short8v*>(Qs + r * LDAP + c * 8) = v;
  }
  {
    int r = t >> 1, h = t & 1;
    int j = jbase + r;
    if (j >= 0) {
      const bf16* krow = qkb + (tb + j) * 96 + 48 + h * 24;
      *reinterpret_cast<short8v*>(Ks + r * LDAP + h * 24) = *reinterpret_cast<const short8v*>(krow);
      *reinterpret_cast<short8v*>(Ks + r * LDAP + h * 24 + 8) = *reinterpret_cast<const short8v*>(krow + 8);
      *reinterpret_cast<short8v*>(Ks + r * LDAP + h * 24 + 16) = *reinterpret_cast<const short8v*>(krow + 16);
    } else {
      *reinterpret_cast<short8v*>(Ks + r * LDAP + h * 24) = z8;
      *reinterpret_cast<short8v*>(Ks + r * LDAP + h * 24 + 8) = z8;
      *reinterpret_cast<short8v*>(Ks + r * LDAP + h * 24 + 16) = z8;
    }
    if (h == 1) {
      *reinterpret_cast<short8v*>(Ks + r * LDAP + 48) = z8;
      *reinterpret_cast<short8v*>(Ks + r * LDAP + 56) = z8;
    }
  }
  __syncthreads();

  int m = lane & 15, g = lane >> 4;

  {
    f32x4 sacc[2][2];
#pragma unroll
    for (int mi = 0; mi < 2; ++mi)
#pragma unroll
      for (int ni = 0; ni < 2; ++ni) sacc[mi][ni] = (f32x4){0.f, 0.f, 0.f, 0.f};
#pragma unroll
    for (int ks = 0; ks < 2; ++ks) {
      int ko = ks * 32 + g * 8;
      fragT aq[2], bk[2];
#pragma unroll
      for (int mi = 0; mi < 2; ++mi)
        aq[mi] = *reinterpret_cast<const fragT*>(Qs + (mi * 16 + m) * LDAP + ko);
#pragma unroll
      for (int ni = 0; ni < 2; ++ni)
        bk[ni] = *reinterpret_cast<const fragT*>(Ks + (w * 32 + ni * 16 + m) * LDAP + ko);
#pragma unroll
      for (int mi = 0; mi < 2; ++mi)
#pragma unroll
        for (int ni = 0; ni < 2; ++ni)
          sacc[mi][ni] = __builtin_amdgcn_mfma_f32_16x16x32_bf16(aq[mi], bk[ni], sacc[mi][ni], 0, 0, 0);
    }
#pragma unroll
    for (int mi = 0; mi < 2; ++mi)
#pragma unroll
      for (int ni = 0; ni < 2; ++ni)
#pragma unroll
        for (int r = 0; r < 4; ++r) {
          int q = mi * 16 + g * 4 + r;
          int key = w * 32 + ni * 16 + m;
          int gi = q0 + q, gj = jbase + key;
          float s = (gj >= 0 && gj <= gi)
                        ? sacc[mi][ni][r] * rs + cmul * (float)(gj - gi)
                        : -INFINITY;
          Ss[q * 132 + key] = s;
        }
  }
  __syncthreads();

  auto loadVreg = [&](int c, short8v* vreg) {
    int j = t >> 3, c8 = t & 7;
    int gj = jbase + c * 32 + j;
    const bf16* vrow = gv + (tb + gj) * (size_t)DIM;
#pragma unroll
    for (int it = 0; it < 6; ++it) {
      int d = (c8 + it * 8) * 8;
      vreg[it] = (gj >= 0) ? *reinterpret_cast<const short8v*>(vrow + d) : z8;
    }
  };
  auto writeV = [&](const short8v* vreg) {
    int j = t >> 3, c8 = t & 7;
    bf16* vb = (bf16*)(smem + ATT_V_OFF);
#pragma unroll
    for (int it = 0; it < 6; ++it) {
      int d = (c8 + it * 8) * 8;
      *reinterpret_cast<short8v*>(vb + ((j >> 2) * 24 + (d >> 4)) * LDAP + (j & 3) * 16 + (d & 15)) = vreg[it];
    }
  };

  {
    int sq = t >> 3, sl = t & 7;
    union { float4 f4[4]; float f[16]; } su;
#pragma unroll
    for (int u2 = 0; u2 < 4; ++u2)
      su.f4[u2] = *reinterpret_cast<const float4*>(Ss + sq * 132 + sl * 16 + u2 * 4);
    __syncthreads();
    float mx = -INFINITY;
#pragma unroll
    for (int e = 0; e < 16; ++e) mx = fmaxf(mx, su.f[e]);
    mx = fmaxf(mx, __shfl_xor(mx, 1));
    mx = fmaxf(mx, __shfl_xor(mx, 2));
    mx = fmaxf(mx, __shfl_xor(mx, 4));
    float pv[16];
    float sum = 0.f;
#pragma unroll
    for (int e = 0; e < 16; ++e) {
      pv[e] = expf(su.f[e] - mx);
      sum += pv[e];
    }
    sum += __shfl_xor(sum, 1);
    sum += __shfl_xor(sum, 2);
    sum += __shfl_xor(sum, 4);
    float inv = 1.f / sum;
    union { bf16 b[16]; short8v s[2]; } pk;
#pragma unroll
    for (int e = 0; e < 16; ++e) pk.b[e] = __float2bfloat16(pv[e] * inv);
    bf16* pr = P + sq * 136 + sl * 16;
    *reinterpret_cast<short8v*>(pr) = pk.s[0];
    *reinterpret_cast<short8v*>(pr + 8) = pk.s[1];
  }
  {
    short8v v0[6];
    loadVreg(0, v0);
    writeV(v0);
  }
  __syncthreads();

  f32x4 oacc[2][6];
#pragma unroll
  for (int mi = 0; mi < 2; ++mi)
#pragma unroll
    for (int nt = 0; nt < 6; ++nt) oacc[mi][nt] = (f32x4){0.f, 0.f, 0.f, 0.f};

  unsigned sbase = (unsigned)(size_t)(&smem[0]);
  unsigned lanebase = (unsigned)(((48 * g + 6 * w) * LDAP + m) * 2);

  for (int c = 0; c < 4; ++c) {
    short8v vnext[6];
    if (c < 3) loadVreg(c + 1, vnext);
    unsigned vaddr = sbase + ATT_V_OFF + lanebase;
    fragT pa0 = *reinterpret_cast<const fragT*>(P + m * 136 + c * 32 + g * 8);
    fragT pa1 = *reinterpret_cast<const fragT*>(P + (16 + m) * 136 + c * 32 + g * 8);
    uint2v trr[12];
#pragma unroll
    for (int nt = 0; nt < 6; ++nt) {
      asm volatile("ds_read_b64_tr_b16 %0, %1" : "=v"(trr[2 * nt]) : "v"(vaddr + nt * 144));
      asm volatile("ds_read_b64_tr_b16 %0, %1" : "=v"(trr[2 * nt + 1]) : "v"(vaddr + nt * 144 + 3456));
    }
    asm volatile("s_waitcnt lgkmcnt(0)" ::: "memory");
    __builtin_amdgcn_sched_barrier(0);
#pragma unroll
    for (int nt = 0; nt < 6; ++nt) {
      union { int4v i4; fragT f; } u2;
      u2.i4 = (int4v){(int)trr[2 * nt].x, (int)trr[2 * nt].y,
                      (int)trr[2 * nt + 1].x, (int)trr[2 * nt + 1].y};
      oacc[0][nt] = __builtin_amdgcn_mfma_f32_16x16x32_bf16(pa0, u2.f, oacc[0][nt], 0, 0, 0);
      oacc[1][nt] = __builtin_amdgcn_mfma_f32_16x16x32_bf16(pa1, u2.f, oacc[1][nt], 0, 0, 0);
    }
    __syncthreads();
    if (c < 3) {
      writeV(vnext);
      __syncthreads();
    }
  }

#pragma unroll
  for (int mi = 0; mi < 2; ++mi)
#pragma unroll
    for (int nt = 0; nt < 6; ++nt) {
#pragma unroll
      for (int r = 0; r < 4; ++r) {
        int q = mi * 16 + g * 4 + r;
        int d = w * 96 + nt * 16 + m;
        ao[(tb + q0 + q) * (size_t)DIM + d] = __float2bfloat16(oacc[mi][nt][r]);
      }
    }
}

// ---------------- project GEMM: gload_lds staging + residual (R8/R11) ------
__global__ __launch_bounds__(256, 4) void project_gl_kernel(
    const bf16* __restrict__ gl, const bf16* __restrict__ at,
    const bf16* __restrict__ wpb, const float* __restrict__ x,
    float* __restrict__ out) {
  __shared__ short As2[128 * 64];  // 16384 B
  __shared__ short Bs2[128 * 64];  // 16384 B
  int t = threadIdx.x;
  int bid = blockIdx.x;
  int logical = (bid & 7) * 192 + (bid >> 3);
  int row0 = (logical / 3) * 128;
  int col0 = (logical % 3) * 128;
  int lane = t & 63, w = t >> 6;
  int wr = w >> 1, wc = w & 1;
  int m = lane & 15, g = lane >> 4;

  int lr = lane >> 3;
  int s8 = lane & 7;
  int cs = s8 ^ lr;

  size_t aoff[4];
  const bf16* gbp[4];
#pragma unroll
  for (int i = 0; i < 4; ++i) {
    int row = w * 32 + i * 8 + lr;
    aoff[i] = (size_t)(row0 + row) * 384 + cs * 8;
    gbp[i] = wpb + (size_t)(col0 + row) * 768 + cs * 8;
  }
  short* la[4];
  short* lb[4];
#pragma unroll
  for (int i = 0; i < 4; ++i) {
    la[i] = As2 + (w * 4 + i) * 512;
    lb[i] = Bs2 + (w * 4 + i) * 512;
  }

  f32x4 acc[4][4];
#pragma unroll
  for (int i = 0; i < 4; ++i)
#pragma unroll
    for (int j = 0; j < 4; ++j) acc[i][j] = (f32x4){0.f, 0.f, 0.f, 0.f};

#pragma unroll
  for (int kt = 0; kt < 12; ++kt) {
    const bf16* ab = (kt < 6) ? gl : at;
    int kk = (kt < 6 ? kt : kt - 6) * 64;
    __syncthreads();
#pragma unroll
    for (int i = 0; i < 4; ++i) gl16(ab + aoff[i] + kk, la[i]);
#pragma unroll
    for (int i = 0; i < 4; ++i) gl16(gbp[i] + kt * 64, lb[i]);
    __syncthreads();
#pragma unroll
    for (int ks = 0; ks < 2; ++ks) {
      int c = ks * 4 + g;
      int cxm = c ^ (m & 7);
      fragT af[4], bfv[4];
#pragma unroll
      for (int mi = 0; mi < 4; ++mi) {
        int R = wr * 64 + mi * 16 + m;
        af[mi] = *reinterpret_cast<const fragT*>(&As2[R * 64 + cxm * 8]);
      }
#pragma unroll
      for (int ni = 0; ni < 4; ++ni) {
        int R = wc * 64 + ni * 16 + m;
        bfv[ni] = *reinterpret_cast<const fragT*>(&Bs2[R * 64 + cxm * 8]);
      }
      __builtin_amdgcn_s_setprio(1);
#pragma unroll
      for (int mi = 0; mi < 4; ++mi)
#pragma unroll
        for (int ni = 0; ni < 4; ++ni)
          acc[mi][ni] = __builtin_amdgcn_mfma_f32_16x16x32_bf16(af[mi], bfv[ni], acc[mi][ni], 0, 0, 0);
      __builtin_amdgcn_s_setprio(0);
    }
  }

#pragma unroll
  for (int mi = 0; mi < 4; ++mi)
#pragma unroll
    for (int ni = 0; ni < 4; ++ni) {
      int d = col0 + wc * 64 + ni * 16 + m;
#pragma unroll
      for (int r = 0; r < 4; ++r) {
        int token = row0 + wr * 64 + mi * 16 + g * 4 + r;
        out[(size_t)token * DIM + d] = x[(size_t)token * DIM + d] + acc[mi][ni][r];
      }
    }
}

extern "C" void kernel_launch(void* const* d_in, const int* in_sizes, int n_in,
                              void* d_out, int out_size, void* d_ws, size_t ws_size,
                              hipStream_t stream) {
  (void)in_sizes; (void)n_in; (void)out_size; (void)ws_size;
  const float* x = (const float*)d_in[0];
  const float* nw = (const float*)d_in[1];
  const float* we = (const float*)d_in[2];
  const float* wp = (const float*)d_in[3];
  const float* pm = (const float*)d_in[4];
  char* ws = (char*)d_ws;
  bf16* xn = (bf16*)(ws);
  bf16* qk = (bf16*)(ws + 50331648);
  bf16* gl = (bf16*)(ws + 62914560);
  bf16* gv = (bf16*)(ws + 113246208);
  bf16* at = (bf16*)(ws + 163577856);
  bf16* web = (bf16*)(ws + 163577856);  // alias: consumed before `at` is written
  bf16* wpb = (bf16*)(ws + 213909504);
  float* out = (float*)d_out;

  hipLaunchKernelGGL(conv_kernel, dim3(512), dim3(256), 0, stream, we, wp, web, wpb);
  hipLaunchKernelGGL(ln_kernel, dim3(NTOK / 4), dim3(256), 0, stream, x, nw, xn);
  hipLaunchKernelGGL(expand_gl_kernel, dim3(512 * 13), dim3(256), 0, stream, xn, web, qk, gl, gv);
  hipLaunchKernelGGL(attn_mfma_kernel, dim3(NBATCH * (S_LEN / 32)), dim3(256), 0, stream, qk, gv, pm, at);
  hipLaunchKernelGGL(project_gl_kernel, dim3(512 * 3), dim3(256), 0, stream, gl, at, wpb, x, out);
}